// Round 6
// baseline (831.656 us; speedup 1.0000x reference)
//
#include <hip/hip_runtime.h>
#include <hip/hip_bf16.h>
#include <stdint.h>

// Problem dims (fixed by setup_inputs)
#define T_DIM 2048
#define I_DIM 4096
#define O_DIM 4096
#define R_DIM 16
#define QBLK  32

typedef __bf16 bf16x8 __attribute__((ext_vector_type(8)));
typedef float  floatx4 __attribute__((ext_vector_type(4)));
typedef unsigned short ushort_t;

__device__ __forceinline__ ushort_t f2bf(float f) {
  unsigned u = __float_as_uint(f);
  u += 0x7FFFu + ((u >> 16) & 1u);   // round-to-nearest-even
  return (ushort_t)(u >> 16);
}

__device__ __forceinline__ float dot4(float4 a, float4 b) {
  return a.x * b.x + a.y * b.y + a.z * b.z + a.w * b.w;
}

// ------------- merged prep: xb=bf16(x) | wb=dequant(q) | xd=alpha*x@down^T
// Block ranges: [0,4096) prep_x, [4096,12288) prep_w, [12288,12544) xd.
__global__ __launch_bounds__(256) void k_prep(const float* __restrict__ x,
                                              const int* __restrict__ q,
                                              const float* __restrict__ scales,
                                              const float* __restrict__ down,
                                              const float* __restrict__ alphap,
                                              ushort_t* __restrict__ xb,
                                              ushort_t* __restrict__ wb,
                                              float* __restrict__ xd) {
  __shared__ float ds[16 * 512];              // 32 KB, used by xd branch only
  const int b = blockIdx.x, tid = threadIdx.x;

  if (b < 4096) {                             // ---- prep_x
    int idx = b * 256 + tid;                  // 8-element chunk id
    const float4* xp = (const float4*)x;
    float4 a = xp[idx * 2], c = xp[idx * 2 + 1];
    union { ushort_t u[8]; uint4 v; } r;
    r.u[0] = f2bf(a.x); r.u[1] = f2bf(a.y); r.u[2] = f2bf(a.z); r.u[3] = f2bf(a.w);
    r.u[4] = f2bf(c.x); r.u[5] = f2bf(c.y); r.u[6] = f2bf(c.z); r.u[7] = f2bf(c.w);
    ((uint4*)xb)[idx] = r.v;
    return;
  }
  if (b < 12288) {                            // ---- prep_w
    int idx = (b - 4096) * 256 + tid;
    int o  = idx >> 9;
    int i0 = (idx & 511) * 8;
    float s = scales[o * (I_DIM / QBLK) + (i0 >> 5)];
    const int4* qp = (const int4*)(q + (size_t)o * I_DIM + i0);
    int4 q0 = qp[0], q1 = qp[1];
    union { ushort_t u[8]; uint4 v; } r;
    r.u[0] = f2bf((float)(q0.x - 8) * s); r.u[1] = f2bf((float)(q0.y - 8) * s);
    r.u[2] = f2bf((float)(q0.z - 8) * s); r.u[3] = f2bf((float)(q0.w - 8) * s);
    r.u[4] = f2bf((float)(q1.x - 8) * s); r.u[5] = f2bf((float)(q1.y - 8) * s);
    r.u[6] = f2bf((float)(q1.z - 8) * s); r.u[7] = f2bf((float)(q1.w - 8) * s);
    ((uint4*)wb)[idx] = r.v;
    return;
  }
  // ---- xd = alpha * (x @ down^T), 8 tokens per block
  {
    const int blk = b - 12288;
    const int tl = tid >> 5, s = tid & 31;
    const int t = blk * 8 + tl;
    float acc[16];
#pragma unroll
    for (int r = 0; r < 16; ++r) acc[r] = 0.f;
    for (int c = 0; c < 8; ++c) {
      const int ib = c * 512;
      __syncthreads();
#pragma unroll
      for (int j = 0; j < 8; ++j) {
        int e = j * 256 + tid;
        int r = e >> 7, col = e & 127;
        ((float4*)ds)[e] = ((const float4*)(down + (size_t)r * I_DIM + ib))[col];
      }
      __syncthreads();
#pragma unroll
      for (int j = 0; j < 4; ++j) {
        float4 xv = ((const float4*)(x + (size_t)t * I_DIM + ib))[s + 32 * j];
#pragma unroll
        for (int r = 0; r < 16; ++r) {
          float4 dv = ((const float4*)ds)[r * 128 + s + 32 * j];
          acc[r] += dot4(xv, dv);
        }
      }
    }
    const float al = alphap[0];
#pragma unroll
    for (int r = 0; r < 16; ++r) {
      float v = acc[r];
      v += __shfl_down(v, 16, 32);
      v += __shfl_down(v, 8, 32);
      v += __shfl_down(v, 4, 32);
      v += __shfl_down(v, 2, 32);
      v += __shfl_down(v, 1, 32);
      if (s == 0) xd[t * 16 + r] = v * al;
    }
  }
}

// ---------------- main GEMM: y = xb @ wb^T + lora-epilogue + bias ------
// R6 mechanism change: NO global_load_lds. Staging via buffer_load->VGPR
// ->ds_write (AITER/hipBLASLt-style). Evidence: R1-R5 all pay 120-210
// cyc/CU per LDS-DMA instr regardless of structure; even m97's plateau
// is ~46 cyc/instr on this path, and the ~2000 TF library kernels avoid
// it entirely. Pipeline per iter:
//   barrier -> ds_write(k, regs) -> issue global loads(k+1)->regs
//   -> barrier -> ds_read frags -> 32 MFMA   (loads fly through all of it)
// 128(T)x64(O) tile, BK=64, 1024 blocks (4/CU, R5-proven), 4 waves,
// XOR-swizzled LDS (write-side swizzle; global reads linear-coalesced).
__global__ __launch_bounds__(256) void k_gemm(const ushort_t* __restrict__ xb,
                                              const ushort_t* __restrict__ wb,
                                              const float* __restrict__ bias,
                                              const float* __restrict__ xd,
                                              const float* __restrict__ up,
                                              float* __restrict__ y) {
  __shared__ __align__(16) ushort_t As[128 * 64];   // 16 KB
  __shared__ __align__(16) ushort_t Bs[64 * 64];    // 8 KB
  const int tid = threadIdx.x;
  const int oT = blockIdx.x * 64, tT = blockIdx.y * 128;
  const int lane = tid & 63;
  const int wv = tid >> 6;
  const int wm = wv >> 1, wn = wv & 1;
  const int quad = lane >> 4, m16 = lane & 15;

  // Per-thread staging geometry: seg_j = tid + 256*j -> row r0+32j, col-seg
  // cg = tid&7 (constant). LDS swizzle c' = cg ^ (r0&7) (r&7 same for all j).
  const int r0 = tid >> 3, cg = tid & 7;
  const int cs = cg ^ (r0 & 7);
  const ushort_t* gA[4];
  ushort_t* lA[4];
#pragma unroll
  for (int j = 0; j < 4; ++j) {
    gA[j] = xb + (size_t)(tT + r0 + 32 * j) * I_DIM + cg * 8;
    lA[j] = As + ((r0 + 32 * j) * 8 + cs) * 8;
  }
  const ushort_t* gB[2];
  ushort_t* lB[2];
#pragma unroll
  for (int j = 0; j < 2; ++j) {
    gB[j] = wb + (size_t)(oT + r0 + 32 * j) * I_DIM + cg * 8;
    lB[j] = Bs + ((r0 + 32 * j) * 8 + cs) * 8;
  }

  floatx4 acc[4][2] = {};
  uint4 va[4], vb[2];

  // prologue: load k-tile 0
#pragma unroll
  for (int j = 0; j < 4; ++j) va[j] = *(const uint4*)(gA[j]);
#pragma unroll
  for (int j = 0; j < 2; ++j) vb[j] = *(const uint4*)(gB[j]);

  for (int kt = 0; kt < I_DIM / 64; ++kt) {
    const int k1 = ((kt + 1) & 63) * 64;      // next k-offset (wraps: harmless)
    __syncthreads();                          // prev readers done; va/vb landed
#pragma unroll
    for (int j = 0; j < 4; ++j) *(uint4*)(lA[j]) = va[j];
#pragma unroll
    for (int j = 0; j < 2; ++j) *(uint4*)(lB[j]) = vb[j];
    // issue next loads now -> in flight through reads+MFMA+next barrier
#pragma unroll
    for (int j = 0; j < 4; ++j) va[j] = *(const uint4*)(gA[j] + k1);
#pragma unroll
    for (int j = 0; j < 2; ++j) vb[j] = *(const uint4*)(gB[j] + k1);
    __syncthreads();                          // tile kt visible in LDS

#pragma unroll
    for (int ks2 = 0; ks2 < 2; ++ks2) {       // two K=32 steps per BK=64
      const int c = ks2 * 4 + quad;
      bf16x8 af[4], bfr[2];
#pragma unroll
      for (int im = 0; im < 4; ++im) {
        int m = wm * 64 + im * 16 + m16;
        af[im] = *(const bf16x8*)(As + (m * 8 + (c ^ (m & 7))) * 8);
      }
#pragma unroll
      for (int in_ = 0; in_ < 2; ++in_) {
        int n = wn * 32 + in_ * 16 + m16;
        bfr[in_] = *(const bf16x8*)(Bs + (n * 8 + (c ^ (n & 7))) * 8);
      }
#pragma unroll
      for (int im = 0; im < 4; ++im)
#pragma unroll
        for (int in_ = 0; in_ < 2; ++in_)
          acc[im][in_] = __builtin_amdgcn_mfma_f32_16x16x32_bf16(
              af[im], bfr[in_], acc[im][in_], 0, 0, 0);
    }
  }

  // Epilogue: y[t][o] = acc + dot16(xd[t], up[o]) + bias[o]
  // C/D layout: row = quad*4+reg, col = lane&15 (m89-verified).
#pragma unroll
  for (int im = 0; im < 4; ++im) {
#pragma unroll
    for (int reg = 0; reg < 4; ++reg) {
      int t = tT + wm * 64 + im * 16 + quad * 4 + reg;
      const float4* xr = (const float4*)(xd + t * 16);
      float4 x0 = xr[0], x1 = xr[1], x2 = xr[2], x3 = xr[3];
#pragma unroll
      for (int in_ = 0; in_ < 2; ++in_) {
        int o = oT + wn * 32 + in_ * 16 + m16;
        const float4* ur = (const float4*)(up + (size_t)o * R_DIM);
        float lv = dot4(x0, ur[0]) + dot4(x1, ur[1]) +
                   dot4(x2, ur[2]) + dot4(x3, ur[3]);
        y[(size_t)t * O_DIM + o] = acc[im][in_][reg] + lv + bias[o];
      }
    }
  }
}

extern "C" void kernel_launch(void* const* d_in, const int* in_sizes, int n_in,
                              void* d_out, int out_size, void* d_ws, size_t ws_size,
                              hipStream_t stream) {
  const float* x      = (const float*)d_in[0];
  const int*   q      = (const int*)d_in[1];
  const float* scales = (const float*)d_in[2];
  const float* up     = (const float*)d_in[3];
  const float* down   = (const float*)d_in[4];
  const float* alpha  = (const float*)d_in[5];
  const float* bias   = (const float*)d_in[6];
  float* y = (float*)d_out;

  // ws layout: xb bf16 [T,I] (16 MB) | wb bf16 [O,I] (32 MB) | xd f32 [T,16]
  ushort_t* xb = (ushort_t*)d_ws;
  ushort_t* wb = (ushort_t*)((char*)d_ws + (size_t)T_DIM * I_DIM * 2);
  float*    xd = (float*)((char*)d_ws + (size_t)T_DIM * I_DIM * 2 + (size_t)O_DIM * I_DIM * 2);

  hipLaunchKernelGGL(k_prep, dim3(4096 + 8192 + 256), dim3(256), 0, stream,
                     x, q, scales, down, alpha, xb, wb, xd);
  hipLaunchKernelGGL(k_gemm, dim3(O_DIM / 64, T_DIM / 128), dim3(256), 0, stream,
                     xb, wb, bias, xd, up, y);
}

// Round 9
// 482.705 us; speedup vs baseline: 1.7229x; 1.7229x over previous
//
#include <hip/hip_runtime.h>
#include <hip/hip_bf16.h>
#include <stdint.h>

// Problem dims (fixed by setup_inputs)
#define T_DIM 2048
#define I_DIM 4096
#define O_DIM 4096
#define R_DIM 16
#define QBLK  32

typedef __bf16 bf16x8 __attribute__((ext_vector_type(8)));
typedef float  floatx4 __attribute__((ext_vector_type(4)));
typedef unsigned short ushort_t;

__device__ __forceinline__ ushort_t f2bf(float f) {
  unsigned u = __float_as_uint(f);
  u += 0x7FFFu + ((u >> 16) & 1u);   // round-to-nearest-even
  return (ushort_t)(u >> 16);
}

__device__ __forceinline__ unsigned pack2bf(float lo, float hi) {
  return (unsigned)f2bf(lo) | ((unsigned)f2bf(hi) << 16);
}

__device__ __forceinline__ float dot4(float4 a, float4 b) {
  return a.x * b.x + a.y * b.y + a.z * b.z + a.w * b.w;
}

// ------------- prep: xb = bf16(x)  |  xd = alpha * x @ down^T
// Block ranges: [0,4096) prep_x, [4096,4352) xd.  (prep_w is gone — W
// dequant is fused into k_gemm.)
__global__ __launch_bounds__(256) void k_prep(const float* __restrict__ x,
                                              const float* __restrict__ down,
                                              const float* __restrict__ alphap,
                                              ushort_t* __restrict__ xb,
                                              float* __restrict__ xd) {
  __shared__ float ds[16 * 512];              // 32 KB, xd branch only
  const int b = blockIdx.x, tid = threadIdx.x;

  if (b < 4096) {                             // ---- prep_x
    int idx = b * 256 + tid;                  // 8-element chunk id
    const float4* xp = (const float4*)x;
    float4 a = xp[idx * 2], c = xp[idx * 2 + 1];
    union { ushort_t u[8]; uint4 v; } r;
    r.u[0] = f2bf(a.x); r.u[1] = f2bf(a.y); r.u[2] = f2bf(a.z); r.u[3] = f2bf(a.w);
    r.u[4] = f2bf(c.x); r.u[5] = f2bf(c.y); r.u[6] = f2bf(c.z); r.u[7] = f2bf(c.w);
    ((uint4*)xb)[idx] = r.v;
    return;
  }
  // ---- xd = alpha * (x @ down^T), 8 tokens per block
  {
    const int blk = b - 4096;
    const int tl = tid >> 5, s = tid & 31;
    const int t = blk * 8 + tl;
    float acc[16];
#pragma unroll
    for (int r = 0; r < 16; ++r) acc[r] = 0.f;
    for (int c = 0; c < 8; ++c) {
      const int ib = c * 512;
      __syncthreads();
#pragma unroll
      for (int j = 0; j < 8; ++j) {
        int e = j * 256 + tid;
        int r = e >> 7, col = e & 127;
        ((float4*)ds)[e] = ((const float4*)(down + (size_t)r * I_DIM + ib))[col];
      }
      __syncthreads();
#pragma unroll
      for (int j = 0; j < 4; ++j) {
        float4 xv = ((const float4*)(x + (size_t)t * I_DIM + ib))[s + 32 * j];
#pragma unroll
        for (int r = 0; r < 16; ++r) {
          float4 dv = ((const float4*)ds)[r * 128 + s + 32 * j];
          acc[r] += dot4(xv, dv);
        }
      }
    }
    const float al = alphap[0];
#pragma unroll
    for (int r = 0; r < 16; ++r) {
      float v = acc[r];
      v += __shfl_down(v, 16, 32);
      v += __shfl_down(v, 8, 32);
      v += __shfl_down(v, 4, 32);
      v += __shfl_down(v, 2, 32);
      v += __shfl_down(v, 1, 32);
      if (s == 0) xd[t * 16 + r] = v * al;
    }
  }
}

// ---------------- fused GEMM: y = xb @ dequant(q,scales)^T + lora + bias
// R9 = R8 with the dequant sign bug fixed: q codes must be loaded as
// SIGNED int4 — R8 used uint4, so (vq.x - 8) wrapped to ~4.29e9 for
// codes 0..7 before the float cast (absmax 3.46e10 matched exactly).
// Mechanism (first clean test this round):
//  * buffer_load->VGPR->ds_write staging (no global_load_lds; R1-R5
//    showed the LDS-DMA path serializes at 120-210 cyc/instr/CU).
//  * W-dequant fused: B-side stages raw q int32 codes, dequants to bf16
//    in-register at ds_write time (kills prep_w + 32 MB wb bounce).
//  * __launch_bounds__(256,4): VGPR cap 128 (R6 spilled at default).
// Tile 128(T) x 64(O), BK=64, grid (64,16)=1024 blocks (4/CU), 4 waves.
// Per iter: barrier -> dequant+ds_write(k) -> issue loads(k+1)
//           -> barrier -> ds_read frags -> 32 MFMA.
__global__ __launch_bounds__(256, 4) void k_gemm(
    const ushort_t* __restrict__ xb, const int* __restrict__ q,
    const float* __restrict__ scales, const float* __restrict__ bias,
    const float* __restrict__ xd, const float* __restrict__ up,
    float* __restrict__ y) {
  __shared__ __align__(16) ushort_t As[128 * 64];   // 16 KB
  __shared__ __align__(16) ushort_t Bs[64 * 64];    // 8 KB
  const int tid = threadIdx.x;
  const int oT = blockIdx.x * 64, tT = blockIdx.y * 128;
  const int lane = tid & 63;
  const int wv = tid >> 6;
  const int wm = wv >> 1, wn = wv & 1;
  const int quad = lane >> 4, m16 = lane & 15;

  // ---- A staging geometry: thread -> (rowA = tid>>3 (+32j), col-seg cg=tid&7)
  const int rA = tid >> 3, cgA = tid & 7;
  const int csA = cgA ^ (rA & 7);                   // LDS XOR swizzle
  const ushort_t* gA = xb + (size_t)(tT + rA) * I_DIM + cgA * 8;  // +32j*I_DIM, +k
  ushort_t* lA = As + (rA * 8 + csA) * 8;           // +32j rows = +2048j ush

  // ---- B staging geometry: thread -> (rowB = tid>>2, 16 codes at c16=(tid&3)*16)
  const int rB = tid >> 2, c16 = (tid & 3) * 16;
  const int cs0 = ((c16 >> 3) ^ (rB & 7)), cs1 = (((c16 >> 3) + 1) ^ (rB & 7));
  const int* gQ = q + (size_t)(oT + rB) * I_DIM + c16;            // +k
  const float* gS = scales + (size_t)(oT + rB) * (I_DIM / QBLK) + (c16 >> 5); // +k/32
  ushort_t* lB0 = Bs + (rB * 8 + cs0) * 8;
  ushort_t* lB1 = Bs + (rB * 8 + cs1) * 8;

  floatx4 acc[4][2] = {};
  uint4 va0, va1, va2, va3;                   // A: 4x16B bf16 (raw bits)
  int4  vq0, vq1, vq2, vq3;                   // B: 16 SIGNED int32 codes
  float vs;                                   // scale for this thread's 16 codes

  // prologue: load k-tile 0
  va0 = *(const uint4*)(gA);
  va1 = *(const uint4*)(gA + 32 * I_DIM);
  va2 = *(const uint4*)(gA + 64 * I_DIM);
  va3 = *(const uint4*)(gA + 96 * I_DIM);
  vq0 = *(const int4*)(gQ);
  vq1 = *(const int4*)(gQ + 4);
  vq2 = *(const int4*)(gQ + 8);
  vq3 = *(const int4*)(gQ + 12);
  vs  = *gS;

  for (int kt = 0; kt < I_DIM / 64; ++kt) {
    const int k1 = ((kt + 1) & 63) * 64;      // next k-offset (wraps: harmless)
    __syncthreads();                          // prev readers done; loads landed
    *(uint4*)(lA)        = va0;               // row rA
    *(uint4*)(lA + 2048) = va1;               // row rA+32  (32 rows * 64 ush)
    *(uint4*)(lA + 4096) = va2;               // row rA+64
    *(uint4*)(lA + 6144) = va3;               // row rA+96
    {
      uint4 b0, b1;
      b0.x = pack2bf((float)(vq0.x - 8) * vs, (float)(vq0.y - 8) * vs);
      b0.y = pack2bf((float)(vq0.z - 8) * vs, (float)(vq0.w - 8) * vs);
      b0.z = pack2bf((float)(vq1.x - 8) * vs, (float)(vq1.y - 8) * vs);
      b0.w = pack2bf((float)(vq1.z - 8) * vs, (float)(vq1.w - 8) * vs);
      b1.x = pack2bf((float)(vq2.x - 8) * vs, (float)(vq2.y - 8) * vs);
      b1.y = pack2bf((float)(vq2.z - 8) * vs, (float)(vq2.w - 8) * vs);
      b1.z = pack2bf((float)(vq3.x - 8) * vs, (float)(vq3.y - 8) * vs);
      b1.w = pack2bf((float)(vq3.z - 8) * vs, (float)(vq3.w - 8) * vs);
      *(uint4*)(lB0) = b0;
      *(uint4*)(lB1) = b1;
    }
    // issue next loads now -> in flight through reads+MFMA+next barrier
    va0 = *(const uint4*)(gA + k1);
    va1 = *(const uint4*)(gA + 32 * I_DIM + k1);
    va2 = *(const uint4*)(gA + 64 * I_DIM + k1);
    va3 = *(const uint4*)(gA + 96 * I_DIM + k1);
    vq0 = *(const int4*)(gQ + k1);
    vq1 = *(const int4*)(gQ + k1 + 4);
    vq2 = *(const int4*)(gQ + k1 + 8);
    vq3 = *(const int4*)(gQ + k1 + 12);
    vs  = *(gS + (k1 >> 5));
    __syncthreads();                          // tile kt visible in LDS

#pragma unroll
    for (int ks2 = 0; ks2 < 2; ++ks2) {       // two K=32 steps per BK=64
      const int c = ks2 * 4 + quad;
      bf16x8 af[4], bfr[2];
#pragma unroll
      for (int im = 0; im < 4; ++im) {
        int m = wm * 64 + im * 16 + m16;
        af[im] = *(const bf16x8*)(As + (m * 8 + (c ^ (m & 7))) * 8);
      }
#pragma unroll
      for (int in_ = 0; in_ < 2; ++in_) {
        int n = wn * 32 + in_ * 16 + m16;
        bfr[in_] = *(const bf16x8*)(Bs + (n * 8 + (c ^ (n & 7))) * 8);
      }
#pragma unroll
      for (int im = 0; im < 4; ++im)
#pragma unroll
        for (int in_ = 0; in_ < 2; ++in_)
          acc[im][in_] = __builtin_amdgcn_mfma_f32_16x16x32_bf16(
              af[im], bfr[in_], acc[im][in_], 0, 0, 0);
    }
  }

  // Epilogue: y[t][o] = acc + dot16(xd[t], up[o]) + bias[o]
  // C/D layout: row = quad*4+reg, col = lane&15 (m89-verified).
#pragma unroll
  for (int im = 0; im < 4; ++im) {
#pragma unroll
    for (int reg = 0; reg < 4; ++reg) {
      int t = tT + wm * 64 + im * 16 + quad * 4 + reg;
      const float4* xr = (const float4*)(xd + t * 16);
      float4 x0 = xr[0], x1 = xr[1], x2 = xr[2], x3 = xr[3];
#pragma unroll
      for (int in_ = 0; in_ < 2; ++in_) {
        int o = oT + wn * 32 + in_ * 16 + m16;
        const float4* ur = (const float4*)(up + (size_t)o * R_DIM);
        float lv = dot4(x0, ur[0]) + dot4(x1, ur[1]) +
                   dot4(x2, ur[2]) + dot4(x3, ur[3]);
        y[(size_t)t * O_DIM + o] = acc[im][in_][reg] + lv + bias[o];
      }
    }
  }
}

extern "C" void kernel_launch(void* const* d_in, const int* in_sizes, int n_in,
                              void* d_out, int out_size, void* d_ws, size_t ws_size,
                              hipStream_t stream) {
  const float* x      = (const float*)d_in[0];
  const int*   q      = (const int*)d_in[1];
  const float* scales = (const float*)d_in[2];
  const float* up     = (const float*)d_in[3];
  const float* down   = (const float*)d_in[4];
  const float* alpha  = (const float*)d_in[5];
  const float* bias   = (const float*)d_in[6];
  float* y = (float*)d_out;

  // ws layout: xb bf16 [T,I] (16 MB) | xd f32 [T,16]
  ushort_t* xb = (ushort_t*)d_ws;
  float*    xd = (float*)((char*)d_ws + (size_t)T_DIM * I_DIM * 2);

  hipLaunchKernelGGL(k_prep, dim3(4096 + 256), dim3(256), 0, stream,
                     x, down, alpha, xb, xd);
  hipLaunchKernelGGL(k_gemm, dim3(O_DIM / 64, T_DIM / 128), dim3(256), 0, stream,
                     xb, q, scales, bias, xd, up, y);
}